// Round 16
// baseline (417.872 us; speedup 1.0000x reference)
//
#include <hip/hip_runtime.h>
#include <cstdint>
#include <cstddef>

#define B_ 4
#define V1 262144   // 64^3
#define C1 64
#define V2 32768    // 32^3
#define C2 128
#define TOTV 131072
#define P_ 34
#define P2_ 1156
#define P3_ 39304
#define SBSTRIDE ((size_t)4 * P3_)   // slice stride in voxel-records ([s][b] layout)

// stats layout (float indices within stats buffer)
#define OFF_S1A 0
#define OFF_S2A 128
#define OFF_CNT1 256
#define OFF_S1B 260
#define OFF_S2B 388
#define OFF_CNT2 516

typedef __bf16 bf16x8 __attribute__((ext_vector_type(8)));
typedef float f32x4 __attribute__((ext_vector_type(4)));

__device__ __forceinline__ float bf2f(unsigned short u) {
    return __builtin_bit_cast(float, (unsigned)u << 16);
}
__device__ __forceinline__ unsigned short f2bf(float f) {
    unsigned u = __builtin_bit_cast(unsigned, f);
    u += 0x7fffu + ((u >> 16) & 1u);     // RTNE
    return (unsigned short)(u >> 16);
}
// fast SiLU: x * 1/(1+e^-x) using v_exp_f32 + v_rcp_f32 (err ~1e-6 rel)
__device__ __forceinline__ float fast_silu(float x) {
    return x * __builtin_amdgcn_rcpf(1.f + __expf(-x));
}

// byte offset of main-step ks's A-base (lane-independent part), CS = 1<<csh
__device__ __forceinline__ int a_ofs(int ks, int csh) {
    int s = ks & ((1 << csh) - 1), tap = ks >> csh;
    int dz = tap / 9, r = tap % 9, dy = r / 3, dx = r % 3;
    return s * (int)(SBSTRIDE * 64) + (dz * P2_ + dy * P_ + dx) * 64;
}

// ---------------- Kernel 01: GN1 stats (blocks <4096) + weight prep/borders (rest) ----------------
__global__ __launch_bounds__(256) void k01_stats_prep(const float* __restrict__ x,
                                                      const int* __restrict__ mask,
                                                      float* __restrict__ stats,
                                                      const float* __restrict__ w1,
                                                      const float* __restrict__ w2,
                                                      const float* __restrict__ wskip,
                                                      unsigned short* __restrict__ w1t,
                                                      unsigned short* __restrict__ w2t,
                                                      int* __restrict__ d1,
                                                      int* __restrict__ d2,
                                                      unsigned short* __restrict__ h1p,
                                                      unsigned short* __restrict__ h2p)
{
    int tid = threadIdx.x;
    if (blockIdx.x >= 4096) {
        int pb = blockIdx.x - 4096;
        if (pb >= 2624) {
            int i = (pb - 2624) * 256 + tid;
            if (i >= 24 * P3_) return;
            int sb = i / P3_, vox = i % P3_;
            int vz = vox / P2_, r = vox % P2_, vy = r / P_, vx = r % P_;
            bool border = (vz == 0) | (vz == 33) | (vy == 0) | (vy == 33) | (vx == 0) | (vx == 33);
            if (!border) return;
            unsigned short* base = (sb < 8) ? (h1p + (size_t)sb * P3_ * 32 + (size_t)vox * 32)
                                            : (h2p + (size_t)(sb - 8) * P3_ * 32 + (size_t)vox * 32);
            uint4 z = {0, 0, 0, 0};
            uint4* b4 = (uint4*)base;
            b4[0] = z; b4[1] = z; b4[2] = z; b4[3] = z;
            return;
        }
        int i = pb * 256 + tid;
        if (pb == 0) {
            int t = tid;
            if (t < 54)               d1[t] = (t + 1 < 54)  ? a_ofs(t + 1, 1) - a_ofs(t, 1) : 0;
            if (t >= 64 && t < 172) { int j = t - 64;
                                      d2[j] = (j + 1 < 108) ? a_ofs(j + 1, 2) - a_ofs(j, 2) : 0; }
        }
        if (i < 54 * 4096) {
            int slab = i >> 12, r = i & 4095;
            int q = r >> 10, n = (r >> 3) & 127, j = r & 7;
            int t = slab >> 1, s = slab & 1;
            int ci = s * 32 + q * 8 + j;
            w1t[i] = f2bf(w1[((size_t)t * 64 + ci) * 128 + n]);
        }
        int i2 = i - 54 * 4096;
        if (i2 >= 0 && i2 < 110 * 4096) {
            int slab = i2 >> 12, r = i2 & 4095;
            int q = r >> 10, n = (r >> 3) & 127, j = r & 7;
            float v;
            if (slab < 108) {
                int t = slab >> 2, s = slab & 3;
                int ci = s * 32 + q * 8 + j;
                v = w2[((size_t)t * 128 + ci) * 128 + n];
            } else {
                int ci = (slab - 108) * 32 + q * 8 + j;
                v = wskip[(size_t)ci * 128 + n];
            }
            w2t[i2] = f2bf(v);
        }
        return;
    }

    __shared__ float ls1[32], ls2[32];
    __shared__ float lcnt;
    if (tid < 32) { ls1[tid] = 0.f; ls2[tid] = 0.f; }
    if (tid == 0) lcnt = 0.f;
    __syncthreads();

    int b  = blockIdx.x & 3;
    int bb = blockIdx.x >> 2;
    int c4 = tid & 15;
    int vl = tid >> 4;

    const float* xb = x + ((size_t)b * V1) * C1;
    const int*   mb = mask + (size_t)b * V1;

    float s1a = 0.f, s2a = 0.f, s1b = 0.f, s2b = 0.f, mc = 0.f;
    for (int ch = bb; ch < V1 / 16; ch += 1024) {
        int v = ch * 16 + vl;
        int m = mb[v];
        if (c4 == 0) mc += (float)m;
        if (m) {
            float4 xv = *(const float4*)(xb + (size_t)v * C1 + c4 * 4);
            s1a += xv.x + xv.y;  s2a += xv.x * xv.x + xv.y * xv.y;
            s1b += xv.z + xv.w;  s2b += xv.z * xv.z + xv.w * xv.w;
        }
    }
    atomicAdd(&ls1[2 * c4],     s1a); atomicAdd(&ls2[2 * c4],     s2a);
    atomicAdd(&ls1[2 * c4 + 1], s1b); atomicAdd(&ls2[2 * c4 + 1], s2b);
    if (c4 == 0) atomicAdd(&lcnt, mc);
    __syncthreads();
    if (tid < 32) {
        atomicAdd(&stats[OFF_S1A + b * 32 + tid], ls1[tid]);
        atomicAdd(&stats[OFF_S2A + b * 32 + tid], ls2[tid]);
    }
    if (tid == 0) atomicAdd(&stats[OFF_CNT1 + b], lcnt);
}

// ------ Kernel 2: GN1 apply + SiLU + downsample -> h1p (padded sliced), xdb (flat), dm, CNT2 ------
__global__ __launch_bounds__(256) void k2_down(const float* __restrict__ x,
                                               const int* __restrict__ mask,
                                               const float* __restrict__ gn1w,
                                               const float* __restrict__ gn1b,
                                               float* __restrict__ stats,
                                               unsigned short* __restrict__ h1p,
                                               unsigned short* __restrict__ xdb,
                                               float* __restrict__ dm)
{
    __shared__ float bcnt;
    int tid = threadIdx.x;
    if (tid == 0) bcnt = 0.f;
    __syncthreads();
    int c  = tid & 63;
    int vl = tid >> 6;
    const size_t ovbase = (size_t)blockIdx.x * 32;
    const int b = (int)(ovbase >> 15);          // uniform per block

    int g = c >> 1;
    float ce   = fmaxf(stats[OFF_CNT1 + b] * 2.f, 1.f);
    float mean = stats[OFF_S1A + b * 32 + g] / ce;
    float var  = stats[OFF_S2A + b * 32 + g] / ce - mean * mean;
    float rinv = rsqrtf(var + 1e-5f);
    float a  = rinv * gn1w[c];
    float bc = gn1b[c] - mean * a;

    const int*   mb = mask + ((size_t)b << 18);
    const float* xb = x + (((size_t)b << 18) << 6);

    float mycnt = 0.f;
    #pragma unroll 2
    for (int it = 0; it < 8; ++it) {
        size_t ov = ovbase + it * 4 + vl;
        int v2 = (int)(ov & 32767);
        int z = v2 >> 10, y = (v2 >> 5) & 31, xk = v2 & 31;

        float hacc = 0.f, xacc = 0.f; int cnt = 0;
        #pragma unroll
        for (int dz = 0; dz < 2; ++dz)
        #pragma unroll
        for (int dy = 0; dy < 2; ++dy)
        #pragma unroll
        for (int dx = 0; dx < 2; ++dx) {
            int v1 = ((2 * z + dz) << 12) | ((2 * y + dy) << 6) | (2 * xk + dx);
            if (mb[v1]) {
                cnt++;
                float xv = xb[(size_t)v1 * 64 + c];
                xacc += xv;
                hacc += fast_silu(fmaf(xv, a, bc));
            }
        }
        float inv = __builtin_amdgcn_rcpf(fmaxf((float)cnt, 1.f));
        int pvox = (z + 1) * P2_ + (y + 1) * P_ + (xk + 1);
        size_t so = ((size_t)(c >> 5) * SBSTRIDE + (size_t)b * P3_ + pvox) * 32 + (c & 31);
        h1p[so] = f2bf(hacc * inv);
        xdb[ov * 64 + c] = f2bf(xacc * inv);
        if (c == 0) {
            float d = (cnt > 0) ? 1.f : 0.f;
            dm[ov] = d;
            mycnt += d;
        }
    }
    if (c == 0) atomicAdd(&bcnt, mycnt);
    __syncthreads();
    if (tid == 0) atomicAdd(&stats[OFF_CNT2 + b], bcnt);
}

// ---------------- MFMA implicit-GEMM conv 3x3x3 (+optional 1x1 skip taps) ----------------
// Wave tile M=64 x N=64 (acc[4][4]=64 VGPR) -> ~130 VGPR total -> 3 waves/SIMD.
// Block = 4 waves = 2 M-waves (y-pairs) x 2 N-waves (co halves): tile M=128 x N=128.
// BK=64 phases (2 K-steps/barrier); W staged via global_load_lds dbuf; counted
// vmcnt(8); setprio on MFMA cluster. conv1 (!SKIP): raw bf16 out in padded-sliced
// layout + fused GN2 stats (shfl reduce -> LDS -> atomicAdd).
template<int CIN, bool SKIP>
__global__ __launch_bounds__(256, 3) void conv3_mfma(
    const unsigned short* __restrict__ srcP,   // padded [CS][4][34^3][32]
    const unsigned short* __restrict__ sksrc,  // flat [TOTV][64] (skip) or null
    const unsigned short* __restrict__ wT,
    const int* __restrict__ tblA,
    const float* __restrict__ bias,
    const float* __restrict__ bias2,
    const float* __restrict__ dm,
    float* __restrict__ outf,
    unsigned short* __restrict__ outb,
    float* __restrict__ statsOut)
{
    constexpr int CS   = CIN / 32;
    constexpr int NKM  = 27 * CS;                 // main K-steps (even)
    constexpr int NPHM = NKM / 2;                 // main phases
    constexpr int NPH  = NPHM + (SKIP ? 1 : 0);   // total phases

    __shared__ short smem[2][8192];   // 2 x 16KB W slab-pairs

    const int tid  = threadIdx.x;
    const int lane = tid & 63;
    const int wv   = tid >> 6;
    const int wm   = wv >> 1;          // M-wave (y-pair)
    const int wn   = wv & 1;           // N-wave (co half)
    // XCD-aware bijective swizzle: 1024 blocks, 8 XCDs, 128-block chunks
    const int orig = blockIdx.x;
    const int blk  = (orig & 7) * 128 + (orig >> 3);
    const int b    = blk >> 8;
    const int z    = (blk >> 3) & 31;
    const int yo   = blk & 7;
    const int y0   = yo * 4 + wm * 2;  // this wave's first y-row (owns y0, y0+1)
    const int vb   = b * 32768;
    const int klo  = (lane >> 4) * 8;
    const int xl   = lane & 15;
    const int rlo  = (lane >> 4) * 4;

    f32x4 acc[4][4];
    #pragma unroll
    for (int f = 0; f < 4; ++f)
        #pragma unroll
        for (int nb = 0; nb < 4; ++nb)
            acc[f][nb] = (f32x4){0.f, 0.f, 0.f, 0.f};

    // per-lane A pointer at step 0: padded coords (z, y0, xl)
    const char* pA = (const char*)srcP +
        (((size_t)b * P3_ + (size_t)(z * P2_ + y0 * P_ + xl)) * 32 + klo) * 2;

    auto loadSkip = [&](int ss, bf16x8* af) {
        const unsigned short* abase = sksrc + ss * 32;
        #pragma unroll
        for (int fy = 0; fy < 2; ++fy)
            #pragma unroll
            for (int fx = 0; fx < 2; ++fx)
                af[fy * 2 + fx] = *(const bf16x8*)(abase +
                    (size_t)(vb + z * 1024 + (y0 + fy) * 32 + fx * 16 + xl) * 64 + klo);
    };

    auto stageW = [&](int pr, int buf) {
        const char* g = (const char*)wT + (size_t)pr * 16384 + wv * 1024 + (lane << 4);
        char* l = (char*)&smem[0][0] + buf * 16384 + wv * 1024;
        #pragma unroll
        for (int j = 0; j < 4; ++j)
            __builtin_amdgcn_global_load_lds(
                (const __attribute__((address_space(1))) unsigned int*)(g + j * 4096),
                (__attribute__((address_space(3))) unsigned int*)(l + j * 4096),
                16, 0, 0);
    };

    auto loadAStep = [&](int ks, bf16x8* af) {
        af[0] = *(const bf16x8*)pA;
        af[1] = *(const bf16x8*)(pA + 1024);
        af[2] = *(const bf16x8*)(pA + 2176);
        af[3] = *(const bf16x8*)(pA + 3200);
        pA += tblA[ks];
    };

    // ---- prologue: W pair 0 -> LDS[0], A steps 0,1 -> afc ----
    bf16x8 afc[8];
    stageW(0, 0);
    loadAStep(0, &afc[0]);
    loadAStep(1, &afc[4]);
    asm volatile("s_waitcnt vmcnt(8)" ::: "memory");
    __builtin_amdgcn_s_barrier();

    int cur = 0;
    #pragma unroll 2
    for (int p = 0; p < NPH; ++p) {
        const bool more = (p + 1 < NPH);
        bf16x8 afn[8] = {{}, {}, {}, {}, {}, {}, {}, {}};
        if (more) {
            stageW(p + 1, cur ^ 1);
            if (2 * p + 2 < NKM) {
                loadAStep(2 * p + 2, &afn[0]);
                loadAStep(2 * p + 3, &afn[4]);
            } else if (SKIP) {
                loadSkip(0, &afn[0]);
                loadSkip(1, &afn[4]);
            }
        }
        __builtin_amdgcn_s_setprio(1);
        #pragma unroll
        for (int ss = 0; ss < 2; ++ss) {
            const short* bp = &smem[0][0] + cur * 8192 + ss * 4096 +
                              (lane >> 4) * 1024 + (wn * 64 + xl) * 8;
            #pragma unroll
            for (int nb = 0; nb < 4; ++nb) {
                bf16x8 bfr = *(const bf16x8*)(bp + nb * 128);
                acc[0][nb] = __builtin_amdgcn_mfma_f32_16x16x32_bf16(afc[ss * 4 + 0], bfr, acc[0][nb], 0, 0, 0);
                acc[1][nb] = __builtin_amdgcn_mfma_f32_16x16x32_bf16(afc[ss * 4 + 1], bfr, acc[1][nb], 0, 0, 0);
                acc[2][nb] = __builtin_amdgcn_mfma_f32_16x16x32_bf16(afc[ss * 4 + 2], bfr, acc[2][nb], 0, 0, 0);
                acc[3][nb] = __builtin_amdgcn_mfma_f32_16x16x32_bf16(afc[ss * 4 + 3], bfr, acc[3][nb], 0, 0, 0);
            }
        }
        __builtin_amdgcn_s_setprio(0);
        if (more) asm volatile("s_waitcnt vmcnt(8)" ::: "memory");
        else      asm volatile("s_waitcnt vmcnt(0)" ::: "memory");
        asm volatile("s_waitcnt lgkmcnt(0)" ::: "memory");
        __builtin_amdgcn_s_barrier();
        #pragma unroll
        for (int j = 0; j < 8; ++j) afc[j] = afn[j];
        cur ^= 1;
    }

    // ---- epilogue ----
    float bv[4];
    #pragma unroll
    for (int nb = 0; nb < 4; ++nb) {
        int co = wn * 64 + nb * 16 + xl;
        if constexpr (SKIP) bv[nb] = bias[co] + bias2[co];
        else                bv[nb] = bias[co];
    }
    if constexpr (SKIP) {
        #pragma unroll
        for (int f = 0; f < 4; ++f) {
            const int fy = f >> 1, fx = f & 1;
            const int vox0 = vb + z * 1024 + (y0 + fy) * 32 + fx * 16 + rlo;
            float4 dm4 = *(const float4*)(dm + vox0);
            #pragma unroll
            for (int j = 0; j < 4; ++j) {
                const float dmx = (j == 0) ? dm4.x : (j == 1) ? dm4.y : (j == 2) ? dm4.z : dm4.w;
                const size_t obase = (size_t)(vox0 + j) * 128 + wn * 64 + xl;
                #pragma unroll
                for (int nb = 0; nb < 4; ++nb) {
                    float o = (acc[f][nb][j] + bv[nb]) * dmx;
                    outf[obase + nb * 16] = o;
                }
            }
        }
    } else {
        // conv1: raw bf16 into padded-sliced layout + GN2 stats partials
        float ps1[4], ps2[4];
        #pragma unroll
        for (int nb = 0; nb < 4; ++nb) { ps1[nb] = 0.f; ps2[nb] = 0.f; }
        #pragma unroll
        for (int f = 0; f < 4; ++f) {
            const int fy = f >> 1, fx = f & 1;
            const int yrow = y0 + fy;
            const int xc0  = fx * 16 + rlo;
            const int vox0 = vb + z * 1024 + yrow * 32 + xc0;
            float4 dm4 = *(const float4*)(dm + vox0);
            #pragma unroll
            for (int j = 0; j < 4; ++j) {
                const float dmx = (j == 0) ? dm4.x : (j == 1) ? dm4.y : (j == 2) ? dm4.z : dm4.w;
                const int pvox = (z + 1) * P2_ + (yrow + 1) * P_ + (xc0 + j + 1);
                const size_t sbase = (size_t)b * P3_ + pvox;
                #pragma unroll
                for (int nb = 0; nb < 4; ++nb) {
                    float o = (acc[f][nb][j] + bv[nb]) * dmx;
                    int co = wn * 64 + nb * 16 + xl;
                    size_t so = ((size_t)(co >> 5) * SBSTRIDE + sbase) * 32 + (co & 31);
                    outb[so] = f2bf(o);
                    ps1[nb] += o; ps2[nb] += o * o;
                }
            }
        }
        // reduce: group g = wn*16 + nb*4 + (xl>>2); 16 lanes per wave share g
        float* lsum = (float*)&smem[0][0];
        __syncthreads();
        if (tid < 64) lsum[tid] = 0.f;
        __syncthreads();
        #pragma unroll
        for (int nb = 0; nb < 4; ++nb) {
            float s1 = ps1[nb], s2 = ps2[nb];
            s1 += __shfl_xor(s1, 1);  s2 += __shfl_xor(s2, 1);
            s1 += __shfl_xor(s1, 2);  s2 += __shfl_xor(s2, 2);
            s1 += __shfl_xor(s1, 16); s2 += __shfl_xor(s2, 16);
            s1 += __shfl_xor(s1, 32); s2 += __shfl_xor(s2, 32);
            if ((lane & 0x33) == 0) {
                int g = wn * 16 + nb * 4 + (xl >> 2);
                atomicAdd(&lsum[g], s1);
                atomicAdd(&lsum[32 + g], s2);
            }
        }
        __syncthreads();
        if (tid < 32) {
            atomicAdd(&statsOut[OFF_S1B + b * 32 + tid], lsum[tid]);
            atomicAdd(&statsOut[OFF_S2B + b * 32 + tid], lsum[32 + tid]);
        }
    }
}

// ---------------- Kernel 5: GN2 apply + SiLU in place on h2p (padded sliced bf16) ----------------
__global__ __launch_bounds__(256) void k5_gn2(unsigned short* __restrict__ h2p,
                                              const float* __restrict__ stats,
                                              const float* __restrict__ dm,
                                              const float* __restrict__ gn2w,
                                              const float* __restrict__ gn2b)
{
    int tid = threadIdx.x;
    int g = tid & 31;
    const int idx0 = blockIdx.x * 2048;
    const int b = (idx0 >> 5) >> 15;

    float ce   = fmaxf(stats[OFF_CNT2 + b] * 4.f, 1.f);
    float mean = stats[OFF_S1B + b * 32 + g] / ce;
    float var  = stats[OFF_S2B + b * 32 + g] / ce - mean * mean;
    float rinv = rsqrtf(var + 1e-5f);
    float4 gw = *(const float4*)(gn2w + g * 4);
    float4 gb = *(const float4*)(gn2b + g * 4);
    float ax = rinv * gw.x, bx = gb.x - mean * ax;
    float ay = rinv * gw.y, by = gb.y - mean * ay;
    float az = rinv * gw.z, bz = gb.z - mean * az;
    float aw = rinv * gw.w, bw = gb.w - mean * aw;

    #pragma unroll 2
    for (int it = 0; it < 8; ++it) {
        int idx = idx0 + it * 256 + tid;
        int v = idx >> 5;
        int v2 = v & 32767;
        float dmv = dm[v];
        int zz = v2 >> 10, yy = (v2 >> 5) & 31, xx = v2 & 31;
        int pvox = (zz + 1) * P2_ + (yy + 1) * P_ + (xx + 1);
        size_t so = ((size_t)(g >> 3) * SBSTRIDE + (size_t)b * P3_ + pvox) * 32 + (g & 7) * 4;
        ushort4 hv = *(const ushort4*)(h2p + so);
        float t;
        ushort4 o;
        t = fmaf(bf2f(hv.x), ax, bx) * dmv; o.x = f2bf(fast_silu(t));
        t = fmaf(bf2f(hv.y), ay, by) * dmv; o.y = f2bf(fast_silu(t));
        t = fmaf(bf2f(hv.z), az, bz) * dmv; o.z = f2bf(fast_silu(t));
        t = fmaf(bf2f(hv.w), aw, bw) * dmv; o.w = f2bf(fast_silu(t));
        *(ushort4*)(h2p + so) = o;
    }
}

extern "C" void kernel_launch(void* const* d_in, const int* in_sizes, int n_in,
                              void* d_out, int out_size, void* d_ws, size_t ws_size,
                              hipStream_t stream)
{
    const float* x     = (const float*)d_in[0];
    const int*   mask  = (const int*)d_in[1];
    const float* gn1w  = (const float*)d_in[2];
    const float* gn1b  = (const float*)d_in[3];
    const float* w1    = (const float*)d_in[4];
    const float* b1    = (const float*)d_in[5];
    const float* gn2w  = (const float*)d_in[6];
    const float* gn2b  = (const float*)d_in[7];
    const float* w2    = (const float*)d_in[8];
    const float* b2    = (const float*)d_in[9];
    const float* wskip = (const float*)d_in[10];
    const float* bskip = (const float*)d_in[11];
    float* out = (float*)d_out;

    char* wsb = (char*)d_ws;
    float*          stats = (float*)wsb;                           // 520 f32
    float*          dm    = (float*)(wsb + 4096);                  // 131072 f32
    unsigned short* h1p   = (unsigned short*)(wsb + 528384);       // 8 sb x 34^3 x 32
    unsigned short* xdb   = (unsigned short*)(wsb + 20652032);     // [TOTV][64]
    unsigned short* h2p   = (unsigned short*)(wsb + 70983680);     // 16 sb x 34^3 x 32
    unsigned short* w1t   = (unsigned short*)(wsb + 111230976);    // 54*4096
    unsigned short* w2t   = (unsigned short*)(wsb + 111673344);    // 110*4096
    int*            d1    = (int*)(wsb + 112574464);               // 54 ints
    int*            d2    = (int*)(wsb + 112574720);               // 108 ints

    hipMemsetAsync(stats, 0, 520 * sizeof(float), stream);

    hipLaunchKernelGGL(k01_stats_prep, dim3(4096 + 2624 + 3685), dim3(256), 0, stream,
                       x, mask, stats, w1, w2, wskip, w1t, w2t, d1, d2, h1p, h2p);
    hipLaunchKernelGGL(k2_down, dim3(4096), dim3(256), 0, stream,
                       x, mask, gn1w, gn1b, stats, h1p, xdb, dm);
    hipLaunchKernelGGL((conv3_mfma<64, false>), dim3(1024), dim3(256), 0, stream,
                       h1p, (const unsigned short*)nullptr, w1t, d1, b1, (const float*)nullptr,
                       dm, (float*)nullptr, h2p, stats);
    hipLaunchKernelGGL(k5_gn2, dim3(2048), dim3(256), 0, stream, h2p, stats, dm, gn2w, gn2b);
    hipLaunchKernelGGL((conv3_mfma<128, true>), dim3(1024), dim3(256), 0, stream,
                       h2p, xdb, w2t, d2, b2, bskip, dm, out, (unsigned short*)nullptr,
                       (float*)nullptr);
}

// Round 17
// 369.873 us; speedup vs baseline: 1.1298x; 1.1298x over previous
//
#include <hip/hip_runtime.h>
#include <cstdint>
#include <cstddef>

#define B_ 4
#define V1 262144   // 64^3
#define C1 64
#define V2 32768    // 32^3
#define C2 128
#define TOTV 131072
#define P_ 34
#define P2_ 1156
#define P3_ 39304
#define SBSTRIDE ((size_t)4 * P3_)   // slice stride in voxel-records ([s][b] layout)

// stats layout (float indices within stats buffer)
#define OFF_S1A 0
#define OFF_S2A 128
#define OFF_CNT1 256
#define OFF_S1B 260
#define OFF_S2B 388
#define OFF_CNT2 516

typedef __bf16 bf16x8 __attribute__((ext_vector_type(8)));
typedef float f32x4 __attribute__((ext_vector_type(4)));

__device__ __forceinline__ float bf2f(unsigned short u) {
    return __builtin_bit_cast(float, (unsigned)u << 16);
}
__device__ __forceinline__ unsigned short f2bf(float f) {
    unsigned u = __builtin_bit_cast(unsigned, f);
    u += 0x7fffu + ((u >> 16) & 1u);     // RTNE
    return (unsigned short)(u >> 16);
}
// fast SiLU: x * 1/(1+e^-x) using v_exp_f32 + v_rcp_f32 (err ~1e-6 rel)
__device__ __forceinline__ float fast_silu(float x) {
    return x * __builtin_amdgcn_rcpf(1.f + __expf(-x));
}

// byte offset of main-step ks's A-base (lane-independent part), CS = 1<<csh
__device__ __forceinline__ int a_ofs(int ks, int csh) {
    int s = ks & ((1 << csh) - 1), tap = ks >> csh;
    int dz = tap / 9, r = tap % 9, dy = r / 3, dx = r % 3;
    return s * (int)(SBSTRIDE * 64) + (dz * P2_ + dy * P_ + dx) * 64;
}

// ---------------- Kernel 01: GN1 stats (blocks <4096) + weight prep/borders (rest) ----------------
__global__ __launch_bounds__(256) void k01_stats_prep(const float* __restrict__ x,
                                                      const int* __restrict__ mask,
                                                      float* __restrict__ stats,
                                                      const float* __restrict__ w1,
                                                      const float* __restrict__ w2,
                                                      const float* __restrict__ wskip,
                                                      unsigned short* __restrict__ w1t,
                                                      unsigned short* __restrict__ w2t,
                                                      int* __restrict__ d1,
                                                      int* __restrict__ d2,
                                                      unsigned short* __restrict__ h1p,
                                                      unsigned short* __restrict__ h2p)
{
    int tid = threadIdx.x;
    if (blockIdx.x >= 4096) {
        int pb = blockIdx.x - 4096;
        if (pb >= 2624) {
            int i = (pb - 2624) * 256 + tid;
            if (i >= 24 * P3_) return;
            int sb = i / P3_, vox = i % P3_;
            int vz = vox / P2_, r = vox % P2_, vy = r / P_, vx = r % P_;
            bool border = (vz == 0) | (vz == 33) | (vy == 0) | (vy == 33) | (vx == 0) | (vx == 33);
            if (!border) return;
            unsigned short* base = (sb < 8) ? (h1p + (size_t)sb * P3_ * 32 + (size_t)vox * 32)
                                            : (h2p + (size_t)(sb - 8) * P3_ * 32 + (size_t)vox * 32);
            uint4 z = {0, 0, 0, 0};
            uint4* b4 = (uint4*)base;
            b4[0] = z; b4[1] = z; b4[2] = z; b4[3] = z;
            return;
        }
        int i = pb * 256 + tid;
        if (pb == 0) {
            int t = tid;
            if (t < 54)               d1[t] = (t + 1 < 54)  ? a_ofs(t + 1, 1) - a_ofs(t, 1) : 0;
            if (t >= 64 && t < 172) { int j = t - 64;
                                      d2[j] = (j + 1 < 108) ? a_ofs(j + 1, 2) - a_ofs(j, 2) : 0; }
        }
        if (i < 54 * 4096) {
            int slab = i >> 12, r = i & 4095;
            int q = r >> 10, n = (r >> 3) & 127, j = r & 7;
            int t = slab >> 1, s = slab & 1;
            int ci = s * 32 + q * 8 + j;
            w1t[i] = f2bf(w1[((size_t)t * 64 + ci) * 128 + n]);
        }
        int i2 = i - 54 * 4096;
        if (i2 >= 0 && i2 < 110 * 4096) {
            int slab = i2 >> 12, r = i2 & 4095;
            int q = r >> 10, n = (r >> 3) & 127, j = r & 7;
            float v;
            if (slab < 108) {
                int t = slab >> 2, s = slab & 3;
                int ci = s * 32 + q * 8 + j;
                v = w2[((size_t)t * 128 + ci) * 128 + n];
            } else {
                int ci = (slab - 108) * 32 + q * 8 + j;
                v = wskip[(size_t)ci * 128 + n];
            }
            w2t[i2] = f2bf(v);
        }
        return;
    }

    __shared__ float ls1[32], ls2[32];
    __shared__ float lcnt;
    if (tid < 32) { ls1[tid] = 0.f; ls2[tid] = 0.f; }
    if (tid == 0) lcnt = 0.f;
    __syncthreads();

    int b  = blockIdx.x & 3;
    int bb = blockIdx.x >> 2;
    int c4 = tid & 15;
    int vl = tid >> 4;

    const float* xb = x + ((size_t)b * V1) * C1;
    const int*   mb = mask + (size_t)b * V1;

    float s1a = 0.f, s2a = 0.f, s1b = 0.f, s2b = 0.f, mc = 0.f;
    for (int ch = bb; ch < V1 / 16; ch += 1024) {
        int v = ch * 16 + vl;
        int m = mb[v];
        if (c4 == 0) mc += (float)m;
        if (m) {
            float4 xv = *(const float4*)(xb + (size_t)v * C1 + c4 * 4);
            s1a += xv.x + xv.y;  s2a += xv.x * xv.x + xv.y * xv.y;
            s1b += xv.z + xv.w;  s2b += xv.z * xv.z + xv.w * xv.w;
        }
    }
    atomicAdd(&ls1[2 * c4],     s1a); atomicAdd(&ls2[2 * c4],     s2a);
    atomicAdd(&ls1[2 * c4 + 1], s1b); atomicAdd(&ls2[2 * c4 + 1], s2b);
    if (c4 == 0) atomicAdd(&lcnt, mc);
    __syncthreads();
    if (tid < 32) {
        atomicAdd(&stats[OFF_S1A + b * 32 + tid], ls1[tid]);
        atomicAdd(&stats[OFF_S2A + b * 32 + tid], ls2[tid]);
    }
    if (tid == 0) atomicAdd(&stats[OFF_CNT1 + b], lcnt);
}

// ------ Kernel 2: GN1 apply + SiLU + downsample -> h1p (padded sliced), xdb (flat), dm, CNT2 ------
__global__ __launch_bounds__(256) void k2_down(const float* __restrict__ x,
                                               const int* __restrict__ mask,
                                               const float* __restrict__ gn1w,
                                               const float* __restrict__ gn1b,
                                               float* __restrict__ stats,
                                               unsigned short* __restrict__ h1p,
                                               unsigned short* __restrict__ xdb,
                                               float* __restrict__ dm)
{
    __shared__ float bcnt;
    int tid = threadIdx.x;
    if (tid == 0) bcnt = 0.f;
    __syncthreads();
    int c  = tid & 63;
    int vl = tid >> 6;
    const size_t ovbase = (size_t)blockIdx.x * 32;
    const int b = (int)(ovbase >> 15);          // uniform per block

    int g = c >> 1;
    float ce   = fmaxf(stats[OFF_CNT1 + b] * 2.f, 1.f);
    float mean = stats[OFF_S1A + b * 32 + g] / ce;
    float var  = stats[OFF_S2A + b * 32 + g] / ce - mean * mean;
    float rinv = rsqrtf(var + 1e-5f);
    float a  = rinv * gn1w[c];
    float bc = gn1b[c] - mean * a;

    const int*   mb = mask + ((size_t)b << 18);
    const float* xb = x + (((size_t)b << 18) << 6);

    float mycnt = 0.f;
    #pragma unroll 2
    for (int it = 0; it < 8; ++it) {
        size_t ov = ovbase + it * 4 + vl;
        int v2 = (int)(ov & 32767);
        int z = v2 >> 10, y = (v2 >> 5) & 31, xk = v2 & 31;

        float hacc = 0.f, xacc = 0.f; int cnt = 0;
        #pragma unroll
        for (int dz = 0; dz < 2; ++dz)
        #pragma unroll
        for (int dy = 0; dy < 2; ++dy)
        #pragma unroll
        for (int dx = 0; dx < 2; ++dx) {
            int v1 = ((2 * z + dz) << 12) | ((2 * y + dy) << 6) | (2 * xk + dx);
            if (mb[v1]) {
                cnt++;
                float xv = xb[(size_t)v1 * 64 + c];
                xacc += xv;
                hacc += fast_silu(fmaf(xv, a, bc));
            }
        }
        float inv = __builtin_amdgcn_rcpf(fmaxf((float)cnt, 1.f));
        int pvox = (z + 1) * P2_ + (y + 1) * P_ + (xk + 1);
        size_t so = ((size_t)(c >> 5) * SBSTRIDE + (size_t)b * P3_ + pvox) * 32 + (c & 31);
        h1p[so] = f2bf(hacc * inv);
        xdb[ov * 64 + c] = f2bf(xacc * inv);
        if (c == 0) {
            float d = (cnt > 0) ? 1.f : 0.f;
            dm[ov] = d;
            mycnt += d;
        }
    }
    if (c == 0) atomicAdd(&bcnt, mycnt);
    __syncthreads();
    if (tid == 0) atomicAdd(&stats[OFF_CNT2 + b], bcnt);
}

// ---------------- MFMA implicit-GEMM conv 3x3x3 (+optional 1x1 skip taps) ----------------
// R15 structure (best known): wave tile M=64 x N=128 (acc[4][8]); block = 4 waves =
// M=256 (8 y-rows at one (b,z)); BK=64 phases (2 K-steps/barrier); W via
// global_load_lds dbuf; counted vmcnt(8); setprio on MFMA cluster.
// conv1 (!SKIP): raw bf16 out in padded-sliced layout + fused GN2 stats.
template<int CIN, bool SKIP>
__global__ __launch_bounds__(256, 2) void conv3_mfma(
    const unsigned short* __restrict__ srcP,   // padded [CS][4][34^3][32]
    const unsigned short* __restrict__ sksrc,  // flat [TOTV][64] (skip) or null
    const unsigned short* __restrict__ wT,
    const int* __restrict__ tblA,
    const float* __restrict__ bias,
    const float* __restrict__ bias2,
    const float* __restrict__ dm,
    float* __restrict__ outf,
    unsigned short* __restrict__ outb,
    float* __restrict__ statsOut)
{
    constexpr int CS   = CIN / 32;
    constexpr int NKM  = 27 * CS;                 // main K-steps (even)
    constexpr int NPHM = NKM / 2;                 // main phases
    constexpr int NPH  = NPHM + (SKIP ? 1 : 0);   // total phases

    __shared__ short smem[2][8192];   // 2 x 16KB W slab-pairs

    const int tid  = threadIdx.x;
    const int lane = tid & 63;
    const int wv   = tid >> 6;
    // XCD-aware bijective swizzle: 512 blocks, 8 XCDs, 64-block chunks
    const int orig = blockIdx.x;
    const int blk  = (orig & 7) * 64 + (orig >> 3);
    const int b    = blk >> 7;
    const int z    = (blk >> 2) & 31;
    const int yo   = blk & 3;
    const int y0   = yo * 8 + wv * 2;  // this wave's first y-row (owns y0, y0+1)
    const int vb   = b * 32768;
    const int klo  = (lane >> 4) * 8;
    const int xl   = lane & 15;
    const int rlo  = (lane >> 4) * 4;

    f32x4 acc[4][8];
    #pragma unroll
    for (int f = 0; f < 4; ++f)
        #pragma unroll
        for (int nb = 0; nb < 8; ++nb)
            acc[f][nb] = (f32x4){0.f, 0.f, 0.f, 0.f};

    // per-lane A pointer at step 0: padded coords (z, y0, xl)
    const char* pA = (const char*)srcP +
        (((size_t)b * P3_ + (size_t)(z * P2_ + y0 * P_ + xl)) * 32 + klo) * 2;

    auto loadSkip = [&](int ss, bf16x8* af) {
        const unsigned short* abase = sksrc + ss * 32;
        #pragma unroll
        for (int fy = 0; fy < 2; ++fy)
            #pragma unroll
            for (int fx = 0; fx < 2; ++fx)
                af[fy * 2 + fx] = *(const bf16x8*)(abase +
                    (size_t)(vb + z * 1024 + (y0 + fy) * 32 + fx * 16 + xl) * 64 + klo);
    };

    auto stageW = [&](int pr, int buf) {
        const char* g = (const char*)wT + (size_t)pr * 16384 + wv * 1024 + (lane << 4);
        char* l = (char*)&smem[0][0] + buf * 16384 + wv * 1024;
        #pragma unroll
        for (int j = 0; j < 4; ++j)
            __builtin_amdgcn_global_load_lds(
                (const __attribute__((address_space(1))) unsigned int*)(g + j * 4096),
                (__attribute__((address_space(3))) unsigned int*)(l + j * 4096),
                16, 0, 0);
    };

    auto loadAStep = [&](int ks, bf16x8* af) {
        af[0] = *(const bf16x8*)pA;
        af[1] = *(const bf16x8*)(pA + 1024);
        af[2] = *(const bf16x8*)(pA + 2176);
        af[3] = *(const bf16x8*)(pA + 3200);
        pA += tblA[ks];
    };

    // ---- prologue: W pair 0 -> LDS[0], A steps 0,1 -> afc ----
    bf16x8 afc[8];
    stageW(0, 0);
    loadAStep(0, &afc[0]);
    loadAStep(1, &afc[4]);
    asm volatile("s_waitcnt vmcnt(8)" ::: "memory");
    __builtin_amdgcn_s_barrier();

    int cur = 0;
    #pragma unroll 2
    for (int p = 0; p < NPH; ++p) {
        const bool more = (p + 1 < NPH);
        bf16x8 afn[8] = {{}, {}, {}, {}, {}, {}, {}, {}};
        if (more) {
            stageW(p + 1, cur ^ 1);
            if (2 * p + 2 < NKM) {
                loadAStep(2 * p + 2, &afn[0]);
                loadAStep(2 * p + 3, &afn[4]);
            } else if (SKIP) {
                loadSkip(0, &afn[0]);
                loadSkip(1, &afn[4]);
            }
        }
        __builtin_amdgcn_s_setprio(1);
        #pragma unroll
        for (int ss = 0; ss < 2; ++ss) {
            const short* bp = &smem[0][0] + cur * 8192 + ss * 4096 +
                              ((lane >> 4) * 128 + xl) * 8;
            #pragma unroll
            for (int nb = 0; nb < 8; ++nb) {
                bf16x8 bfr = *(const bf16x8*)(bp + nb * 128);
                acc[0][nb] = __builtin_amdgcn_mfma_f32_16x16x32_bf16(afc[ss * 4 + 0], bfr, acc[0][nb], 0, 0, 0);
                acc[1][nb] = __builtin_amdgcn_mfma_f32_16x16x32_bf16(afc[ss * 4 + 1], bfr, acc[1][nb], 0, 0, 0);
                acc[2][nb] = __builtin_amdgcn_mfma_f32_16x16x32_bf16(afc[ss * 4 + 2], bfr, acc[2][nb], 0, 0, 0);
                acc[3][nb] = __builtin_amdgcn_mfma_f32_16x16x32_bf16(afc[ss * 4 + 3], bfr, acc[3][nb], 0, 0, 0);
            }
        }
        __builtin_amdgcn_s_setprio(0);
        if (more) asm volatile("s_waitcnt vmcnt(8)" ::: "memory");
        else      asm volatile("s_waitcnt vmcnt(0)" ::: "memory");
        asm volatile("s_waitcnt lgkmcnt(0)" ::: "memory");
        __builtin_amdgcn_s_barrier();
        #pragma unroll
        for (int j = 0; j < 8; ++j) afc[j] = afn[j];
        cur ^= 1;
    }

    // ---- epilogue ----
    float bv[8];
    #pragma unroll
    for (int nb = 0; nb < 8; ++nb) {
        int co = nb * 16 + xl;
        if constexpr (SKIP) bv[nb] = bias[co] + bias2[co];
        else                bv[nb] = bias[co];
    }
    if constexpr (SKIP) {
        #pragma unroll
        for (int f = 0; f < 4; ++f) {
            const int fy = f >> 1, fx = f & 1;
            const int vox0 = vb + z * 1024 + (y0 + fy) * 32 + fx * 16 + rlo;
            float4 dm4 = *(const float4*)(dm + vox0);
            #pragma unroll
            for (int j = 0; j < 4; ++j) {
                const float dmx = (j == 0) ? dm4.x : (j == 1) ? dm4.y : (j == 2) ? dm4.z : dm4.w;
                const size_t obase = (size_t)(vox0 + j) * 128 + xl;
                #pragma unroll
                for (int nb = 0; nb < 8; ++nb) {
                    float o = (acc[f][nb][j] + bv[nb]) * dmx;
                    outf[obase + nb * 16] = o;
                }
            }
        }
    } else {
        // conv1: raw bf16 into padded-sliced layout + GN2 stats partials
        float ps1[8], ps2[8];
        #pragma unroll
        for (int nb = 0; nb < 8; ++nb) { ps1[nb] = 0.f; ps2[nb] = 0.f; }
        #pragma unroll
        for (int f = 0; f < 4; ++f) {
            const int fy = f >> 1, fx = f & 1;
            const int yrow = y0 + fy;
            const int xc0  = fx * 16 + rlo;
            const int vox0 = vb + z * 1024 + yrow * 32 + xc0;
            float4 dm4 = *(const float4*)(dm + vox0);
            #pragma unroll
            for (int j = 0; j < 4; ++j) {
                const float dmx = (j == 0) ? dm4.x : (j == 1) ? dm4.y : (j == 2) ? dm4.z : dm4.w;
                const int pvox = (z + 1) * P2_ + (yrow + 1) * P_ + (xc0 + j + 1);
                const size_t sbase = (size_t)b * P3_ + pvox;
                #pragma unroll
                for (int nb = 0; nb < 8; ++nb) {
                    float o = (acc[f][nb][j] + bv[nb]) * dmx;
                    int co = nb * 16 + xl;
                    size_t so = ((size_t)(co >> 5) * SBSTRIDE + sbase) * 32 + (co & 31);
                    outb[so] = f2bf(o);
                    ps1[nb] += o; ps2[nb] += o * o;
                }
            }
        }
        // cross-lane reduce into groups g = nb*4 + (xl>>2); 16 lanes per group
        float* lsum = (float*)&smem[0][0];
        __syncthreads();
        if (tid < 64) lsum[tid] = 0.f;
        __syncthreads();
        #pragma unroll
        for (int nb = 0; nb < 8; ++nb) {
            float s1 = ps1[nb], s2 = ps2[nb];
            s1 += __shfl_xor(s1, 1);  s2 += __shfl_xor(s2, 1);
            s1 += __shfl_xor(s1, 2);  s2 += __shfl_xor(s2, 2);
            s1 += __shfl_xor(s1, 16); s2 += __shfl_xor(s2, 16);
            s1 += __shfl_xor(s1, 32); s2 += __shfl_xor(s2, 32);
            if ((lane & 0x33) == 0) {
                int g = nb * 4 + (xl >> 2);
                atomicAdd(&lsum[g], s1);
                atomicAdd(&lsum[32 + g], s2);
            }
        }
        __syncthreads();
        if (tid < 32) {
            atomicAdd(&statsOut[OFF_S1B + b * 32 + tid], lsum[tid]);
            atomicAdd(&statsOut[OFF_S2B + b * 32 + tid], lsum[32 + tid]);
        }
    }
}

// ---------------- Kernel 5: GN2 apply + SiLU in place on h2p (padded sliced bf16) ----------------
__global__ __launch_bounds__(256) void k5_gn2(unsigned short* __restrict__ h2p,
                                              const float* __restrict__ stats,
                                              const float* __restrict__ dm,
                                              const float* __restrict__ gn2w,
                                              const float* __restrict__ gn2b)
{
    int tid = threadIdx.x;
    int g = tid & 31;
    const int idx0 = blockIdx.x * 2048;
    const int b = (idx0 >> 5) >> 15;

    float ce   = fmaxf(stats[OFF_CNT2 + b] * 4.f, 1.f);
    float mean = stats[OFF_S1B + b * 32 + g] / ce;
    float var  = stats[OFF_S2B + b * 32 + g] / ce - mean * mean;
    float rinv = rsqrtf(var + 1e-5f);
    float4 gw = *(const float4*)(gn2w + g * 4);
    float4 gb = *(const float4*)(gn2b + g * 4);
    float ax = rinv * gw.x, bx = gb.x - mean * ax;
    float ay = rinv * gw.y, by = gb.y - mean * ay;
    float az = rinv * gw.z, bz = gb.z - mean * az;
    float aw = rinv * gw.w, bw = gb.w - mean * aw;

    #pragma unroll 2
    for (int it = 0; it < 8; ++it) {
        int idx = idx0 + it * 256 + tid;
        int v = idx >> 5;
        int v2 = v & 32767;
        float dmv = dm[v];
        int zz = v2 >> 10, yy = (v2 >> 5) & 31, xx = v2 & 31;
        int pvox = (zz + 1) * P2_ + (yy + 1) * P_ + (xx + 1);
        size_t so = ((size_t)(g >> 3) * SBSTRIDE + (size_t)b * P3_ + pvox) * 32 + (g & 7) * 4;
        ushort4 hv = *(const ushort4*)(h2p + so);
        float t;
        ushort4 o;
        t = fmaf(bf2f(hv.x), ax, bx) * dmv; o.x = f2bf(fast_silu(t));
        t = fmaf(bf2f(hv.y), ay, by) * dmv; o.y = f2bf(fast_silu(t));
        t = fmaf(bf2f(hv.z), az, bz) * dmv; o.z = f2bf(fast_silu(t));
        t = fmaf(bf2f(hv.w), aw, bw) * dmv; o.w = f2bf(fast_silu(t));
        *(ushort4*)(h2p + so) = o;
    }
}

extern "C" void kernel_launch(void* const* d_in, const int* in_sizes, int n_in,
                              void* d_out, int out_size, void* d_ws, size_t ws_size,
                              hipStream_t stream)
{
    const float* x     = (const float*)d_in[0];
    const int*   mask  = (const int*)d_in[1];
    const float* gn1w  = (const float*)d_in[2];
    const float* gn1b  = (const float*)d_in[3];
    const float* w1    = (const float*)d_in[4];
    const float* b1    = (const float*)d_in[5];
    const float* gn2w  = (const float*)d_in[6];
    const float* gn2b  = (const float*)d_in[7];
    const float* w2    = (const float*)d_in[8];
    const float* b2    = (const float*)d_in[9];
    const float* wskip = (const float*)d_in[10];
    const float* bskip = (const float*)d_in[11];
    float* out = (float*)d_out;

    char* wsb = (char*)d_ws;
    float*          stats = (float*)wsb;                           // 520 f32
    float*          dm    = (float*)(wsb + 4096);                  // 131072 f32
    unsigned short* h1p   = (unsigned short*)(wsb + 528384);       // 8 sb x 34^3 x 32
    unsigned short* xdb   = (unsigned short*)(wsb + 20652032);     // [TOTV][64]
    unsigned short* h2p   = (unsigned short*)(wsb + 70983680);     // 16 sb x 34^3 x 32
    unsigned short* w1t   = (unsigned short*)(wsb + 111230976);    // 54*4096
    unsigned short* w2t   = (unsigned short*)(wsb + 111673344);    // 110*4096
    int*            d1    = (int*)(wsb + 112574464);               // 54 ints
    int*            d2    = (int*)(wsb + 112574720);               // 108 ints

    hipMemsetAsync(stats, 0, 520 * sizeof(float), stream);

    hipLaunchKernelGGL(k01_stats_prep, dim3(4096 + 2624 + 3685), dim3(256), 0, stream,
                       x, mask, stats, w1, w2, wskip, w1t, w2t, d1, d2, h1p, h2p);
    hipLaunchKernelGGL(k2_down, dim3(4096), dim3(256), 0, stream,
                       x, mask, gn1w, gn1b, stats, h1p, xdb, dm);
    hipLaunchKernelGGL((conv3_mfma<64, false>), dim3(512), dim3(256), 0, stream,
                       h1p, (const unsigned short*)nullptr, w1t, d1, b1, (const float*)nullptr,
                       dm, (float*)nullptr, h2p, stats);
    hipLaunchKernelGGL(k5_gn2, dim3(2048), dim3(256), 0, stream, h2p, stats, dm, gn2w, gn2b);
    hipLaunchKernelGGL((conv3_mfma<128, true>), dim3(512), dim3(256), 0, stream,
                       h2p, xdb, w2t, d2, b2, bskip, dm, out, (unsigned short*)nullptr,
                       (float*)nullptr);
}